// Round 2
// baseline (347.172 us; speedup 1.0000x reference)
//
#include <hip/hip_runtime.h>
#include <hip/hip_bf16.h>

typedef __hip_bfloat16 bf16;
typedef __attribute__((ext_vector_type(8))) short short8;   // 8 bf16 (4 VGPRs)
typedef __attribute__((ext_vector_type(4))) float f32x4;    // MFMA accumulator

#define MFMA16(a, b, c) __builtin_amdgcn_mfma_f32_16x16x32_bf16((a), (b), (c), 0, 0, 0)

// dual-mode float load: f32 ? float buffer : bf16 buffer (same element index)
static __device__ __forceinline__ float ldf(const void* p, long long i, bool f32) {
    return f32 ? ((const float*)p)[i] : __bfloat162float(((const bf16*)p)[i]);
}

static __device__ __forceinline__ short f2bs(float v) {
    union { bf16 h; short s; } u; u.h = __float2bfloat16(v); return u.s;
}

// ---------------------------------------------------------------- encoding sniffer
// flags[0]: x is fp32?  flags[1]: weights are fp32?  flags[2]: edge_index is int64?
// MEASURED (R1 NaN-fail + R8 gating probe): this harness delivers x=fp32, W=fp32, out=fp32.
__global__ __launch_bounds__(256, 4)
void sniff_kernel(const void* __restrict__ x, const void* __restrict__ w,
                  const int* __restrict__ ei, int E, int* __restrict__ flags) {
    __shared__ int cnt;
    if (threadIdx.x == 0) cnt = 0;
    __syncthreads();
    if (blockIdx.x < 2) {
        const unsigned short* u = (const unsigned short*)(blockIdx.x == 0 ? x : w);
        int bad = 0;
        for (int i = threadIdx.x; i < 4096; i += 256) {
            unsigned e = (u[i] >> 7) & 0xFF;
            if (e >= 0xA0) bad++;
        }
        atomicAdd(&cnt, bad);
        __syncthreads();
        if (threadIdx.x == 0) flags[blockIdx.x] = (cnt > 16) ? 1 : 0;
    } else {
        int nz = 0;
        for (int i = threadIdx.x; i < 1024; i += 256)
            if (ei[2 * i + 1] != 0) nz++;
        atomicAdd(&cnt, nz);
        __syncthreads();
        if (threadIdx.x == 0) flags[2] = (cnt == 0) ? 1 : 0;
    }
}

static __device__ __forceinline__ int ld_src(const int* ei, int E, int e, bool i64) {
    return i64 ? ei[2 * e] : ei[e];
}
static __device__ __forceinline__ int ld_dst(const int* ei, int E, int e, bool i64) {
    return i64 ? ei[2 * (E + e)] : ei[E + e];
}

// ---------------------------------------------------------------- bucket CSR build
// shift=9: bucket b owns dst in [b*512, (b+1)*512). NB = ceil(N/512) <= 256.

// Pass A: global bucket histogram (LDS hist per block, 1 global add per bucket)
__global__ __launch_bounds__(256, 4)
void bhist_kernel(const int* __restrict__ ei, int E, const int* __restrict__ flags,
                  int shift, int NB, int* __restrict__ bucketCount) {
    __shared__ int h[256];
    for (int i = threadIdx.x; i < 256; i += 256) h[i] = 0;
    __syncthreads();
    bool i64 = flags[2] != 0;
    int base = blockIdx.x * 4096;
    for (int i = 0; i < 16; i++) {
        int e = base + i * 256 + threadIdx.x;
        if (e < E) atomicAdd(&h[ld_dst(ei, E, e, i64) >> shift], 1);
    }
    __syncthreads();
    for (int i = threadIdx.x; i < NB; i += 256)
        if (h[i]) atomicAdd(&bucketCount[i], h[i]);
}

// Pass B scan: bucketBase = exclusive scan; bcursor seeded with bases
__global__ __launch_bounds__(256, 4)
void bscan_kernel(const int* __restrict__ bucketCount, int NB,
                  int* __restrict__ bucketBase, int* __restrict__ bcursor, int E) {
    __shared__ int bs[256];
    int v = ((int)threadIdx.x < NB) ? bucketCount[threadIdx.x] : 0;
    bs[threadIdx.x] = v;
    __syncthreads();
    for (int off = 1; off < 256; off <<= 1) {
        int t = ((int)threadIdx.x >= off) ? bs[threadIdx.x - off] : 0;
        __syncthreads();
        bs[threadIdx.x] += t;
        __syncthreads();
    }
    int excl = bs[threadIdx.x] - v;
    if ((int)threadIdx.x < NB) { bucketBase[threadIdx.x] = excl; bcursor[threadIdx.x] = excl; }
    if (threadIdx.x == 0) bucketBase[NB] = E;
}

// Pass C: partition edges into bucket-contiguous ebuf (int2: x=src, y=dst)
__global__ __launch_bounds__(256, 4)
void bpart_kernel(const int* __restrict__ ei, int E, const int* __restrict__ flags,
                  int shift, int NB, int* __restrict__ bcursor, int2* __restrict__ ebuf) {
    __shared__ int h[256];
    __shared__ int gofs[256];
    for (int i = threadIdx.x; i < 256; i += 256) h[i] = 0;
    __syncthreads();
    bool i64 = flags[2] != 0;
    int base = blockIdx.x * 4096;
    // sweep 1: local histogram
    for (int i = 0; i < 16; i++) {
        int e = base + i * 256 + threadIdx.x;
        if (e < E) atomicAdd(&h[ld_dst(ei, E, e, i64) >> shift], 1);
    }
    __syncthreads();
    // claim contiguous global ranges (1 atomic per bucket per block)
    if ((int)threadIdx.x < NB) {
        int c = h[threadIdx.x];
        gofs[threadIdx.x] = c ? atomicAdd(&bcursor[threadIdx.x], c) : 0;
    }
    __syncthreads();
    for (int i = threadIdx.x; i < 256; i += 256) h[i] = 0;
    __syncthreads();
    // sweep 2: write edges into claimed dense runs
    for (int i = 0; i < 16; i++) {
        int e = base + i * 256 + threadIdx.x;
        if (e < E) {
            int s = ld_src(ei, E, e, i64), d = ld_dst(ei, E, e, i64);
            int b = d >> shift;
            int p = atomicAdd(&h[b], 1);
            ebuf[gofs[b] + p] = make_int2(s, d);
        }
    }
}

// Pass D: one block per bucket — local count, scan, rowptr+dinv write, csr fill.
// All csr writes land in one block's ~32KB window (single XCD L2; no line ping-pong).
__global__ __launch_bounds__(256, 2)
void bbuild_kernel(const int2* __restrict__ ebuf, const int* __restrict__ bucketBase,
                   int shift, int N, int E, int* __restrict__ rowptr,
                   float* __restrict__ dinv, int* __restrict__ csr_src) {
    __shared__ int cnt[1024];
    __shared__ int exc[1024];
    __shared__ int bs[256];
    int b = blockIdx.x;
    int nodeBase = b << shift;
    int width = 1 << shift;
    int nn = N - nodeBase; if (nn > width) nn = width;
    int beg = bucketBase[b], end = bucketBase[b + 1];
    for (int i = threadIdx.x; i < width; i += 256) cnt[i] = 0;
    __syncthreads();
    for (int e = beg + threadIdx.x; e < end; e += 256)
        atomicAdd(&cnt[ebuf[e].y - nodeBase], 1);
    __syncthreads();
    // exclusive scan of cnt[0..width)
    int per = width / 256;          // 2 at shift=9
    int s = 0;
    int base4 = threadIdx.x * per;
    for (int i = 0; i < per; i++) s += cnt[base4 + i];
    bs[threadIdx.x] = s;
    __syncthreads();
    for (int off = 1; off < 256; off <<= 1) {
        int t = ((int)threadIdx.x >= off) ? bs[threadIdx.x - off] : 0;
        __syncthreads();
        bs[threadIdx.x] += t;
        __syncthreads();
    }
    int run = bs[threadIdx.x] - s;
    for (int i = 0; i < per; i++) { exc[base4 + i] = run; run += cnt[base4 + i]; }
    __syncthreads();
    // rowptr + dinv (coalesced)
    for (int i = threadIdx.x; i < nn; i += 256) {
        int node = nodeBase + i;
        rowptr[node] = beg + exc[i];
        dinv[node] = rsqrtf((float)cnt[i] + 1.0f);
    }
    __syncthreads();
    for (int i = threadIdx.x; i < width; i += 256) cnt[i] = 0;
    __syncthreads();
    // csr fill within local window
    for (int e = beg + threadIdx.x; e < end; e += 256) {
        int2 v = ebuf[e];
        int l = v.y - nodeBase;
        int p = atomicAdd(&cnt[l], 1);
        csr_src[beg + exc[l] + p] = v.x;
    }
    if (b == 0 && threadIdx.x == 0) rowptr[N] = E;
}

// ---------------------------------------------------------------- weight -> MFMA B-fragment packs
// frag f = kstep*ntiles + ntile; slot s = f*64 + lane; element j (0..7):
//   W[kstep*32 + (lane>>4)*8 + j][ntile*16 + (lane&15)]  (fw-aware fp32/bf16 read)
__global__ __launch_bounds__(256, 4)
void repack_kernel(const void* __restrict__ W1, const void* __restrict__ W2,
                   const void* __restrict__ Wl, const int* __restrict__ flags,
                   bf16* __restrict__ Bp1, bf16* __restrict__ Bp2, bf16* __restrict__ Bp3) {
    bool fw = flags[1] != 0;
    const void* W; bf16* Bp; int ntiles, nc, nfrag;
    if (blockIdx.x == 0)      { W = W1; Bp = Bp1; ntiles = 4; nc = 64; nfrag = 16; }
    else if (blockIdx.x == 1) { W = W2; Bp = Bp2; ntiles = 2; nc = 32; nfrag = 4;  }
    else                      { W = Wl; Bp = Bp3; ntiles = 2; nc = 32; nfrag = 14; }
    for (int s = threadIdx.x; s < nfrag * 64; s += 256) {
        int f = s >> 6, lane = s & 63;
        int kstep = f / ntiles, ntile = f % ntiles;
        int n = ntile * 16 + (lane & 15);
        int kbase = kstep * 32 + (lane >> 4) * 8;
#pragma unroll
        for (int j = 0; j < 8; j++)
            Bp[s * 8 + j] = __float2bfloat16(ldf(W, (long long)(kbase + j) * nc + n, fw));
    }
}

// ---------------------------------------------------------------- x -> xb (bf16), both source dtypes
__global__ __launch_bounds__(256, 4)
void cvt_x_kernel(const void* __restrict__ x, const int* __restrict__ flags,
                  short* __restrict__ xb, long long total8) {
    long long i = (long long)blockIdx.x * 256 + threadIdx.x;
    if (i >= total8) return;
    bool fx = flags[0] != 0;
    short8 o;
    if (fx) {
        const float4* xf = (const float4*)x;
        float4 a = xf[i * 2], b = xf[i * 2 + 1];
        o[0] = f2bs(a.x); o[1] = f2bs(a.y); o[2] = f2bs(a.z); o[3] = f2bs(a.w);
        o[4] = f2bs(b.x); o[5] = f2bs(b.y); o[6] = f2bs(b.z); o[7] = f2bs(b.w);
    } else {
        o = ((const short8*)x)[i];
    }
    ((short8*)xb)[i] = o;
}

// ---------------------------------------------------------------- GEMM1 (MFMA): xb[N,128]@W1 -> h1g[N,64] f32
// Epilogue scales row r by dinv[r]:  g = dinv * (x@W1).  The per-edge norm
// dinv[src]*dinv[dst] then factors out of the gather (dst part applied once).
__global__ __launch_bounds__(256, 3)
void gemm1_mfma_kernel(const short* __restrict__ xb, const bf16* __restrict__ Bpack,
                       const float* __restrict__ dinv, float* __restrict__ h1g, int N) {
    int lane = threadIdx.x & 63, wave = threadIdx.x >> 6;
    int m = lane & 15, quad = lane >> 4;
    int base = blockIdx.x * 128 + wave * 32;
    if (base >= N) return;
    const short8* bp = (const short8*)Bpack;
    short8 B[16];
#pragma unroll
    for (int i = 0; i < 16; i++) B[i] = bp[i * 64 + lane];
    if (base + 32 <= N) {
#pragma unroll
        for (int t = 0; t < 2; t++) {
            int r0 = base + t * 16;
            const short* xr = &xb[(long long)(r0 + m) * 128 + quad * 8];
            short8 A[4];
#pragma unroll
            for (int k = 0; k < 4; k++) A[k] = *(const short8*)(xr + k * 32);
            f32x4 acc[4];
#pragma unroll
            for (int nt = 0; nt < 4; nt++) acc[nt] = (f32x4){0.f, 0.f, 0.f, 0.f};
#pragma unroll
            for (int k = 0; k < 4; k++) {
#pragma unroll
                for (int nt = 0; nt < 4; nt++) acc[nt] = MFMA16(A[k], B[k * 4 + nt], acc[nt]);
            }
            // C/D: col = lane&15, row = quad*4 + r  [m89/m91]
            float dv[4];
#pragma unroll
            for (int r = 0; r < 4; r++) dv[r] = dinv[r0 + quad * 4 + r];
            float* o = &h1g[(long long)(r0 + quad * 4) * 64 + m];
#pragma unroll
            for (int nt = 0; nt < 4; nt++) {
#pragma unroll
                for (int r = 0; r < 4; r++) o[(long long)r * 64 + nt * 16] = acc[nt][r] * dv[r];
            }
        }
    } else {
#pragma unroll
        for (int t = 0; t < 2; t++) {
            int r0 = base + t * 16;
            int row = r0 + m;
            short8 A[4];
#pragma unroll
            for (int k = 0; k < 4; k++) A[k] = (short8){0,0,0,0,0,0,0,0};
            if (row < N) {
                const short* xr = &xb[(long long)row * 128 + quad * 8];
#pragma unroll
                for (int k = 0; k < 4; k++) A[k] = *(const short8*)(xr + k * 32);
            }
            f32x4 acc[4];
#pragma unroll
            for (int nt = 0; nt < 4; nt++) acc[nt] = (f32x4){0.f, 0.f, 0.f, 0.f};
#pragma unroll
            for (int k = 0; k < 4; k++) {
#pragma unroll
                for (int nt = 0; nt < 4; nt++) acc[nt] = MFMA16(A[k], B[k * 4 + nt], acc[nt]);
            }
#pragma unroll
            for (int r = 0; r < 4; r++) {
                int orow = r0 + quad * 4 + r;
                if (orow < N) {
                    float dv = dinv[orow];
                    float* o = &h1g[(long long)orow * 64 + m];
#pragma unroll
                    for (int nt = 0; nt < 4; nt++) o[nt * 16] = acc[nt][r] * dv;
                }
            }
        }
    }
}

// ---------------------------------------------------------------- gather layer 1: one wave per node -> h1b (bf16)
// R-new: scalar-index inner loop. node is made wave-uniform via readfirstlane so
// csr_src[...] has a uniform address -> s_load (SMEM pipe, merged dwordx4/x8).
// Removes the 2 ds_bpermute/edge (~30us of LDS-pipe time) and all per-edge dinv
// work (rows are pre-scaled by dinv in the GEMM epilogue:
//   out = dvd*(sum_nb g[s] + g[node]) + b).  Tail via scalar clamp + 0/1 mask
// (v_fmac with SGPR mask).  16 independent row loads in flight per wave.
__global__ __launch_bounds__(256, 8)
void gather1_kernel(const float* __restrict__ h1g, const float* __restrict__ dinv,
                    const int* __restrict__ rowptr, const int* __restrict__ csr_src,
                    const void* __restrict__ b1, const int* __restrict__ flags,
                    bf16* __restrict__ h1b, int N) {
    bool fw = flags[1] != 0;
    int lane = threadIdx.x & 63;
    int wv = __builtin_amdgcn_readfirstlane(threadIdx.x >> 6);
    int node = blockIdx.x * 4 + wv;
    if (node >= N) return;
    int beg = rowptr[node], end = rowptr[node + 1];
    float dvd = dinv[node];
    const float* hL = h1g + lane;
    float acc = 0.f;
    for (int b = beg; b < end; b += 16) {
        float v[16], m[16];
#pragma unroll
        for (int u = 0; u < 16; u++) {
            int i = b + u;
            int s = csr_src[(i < end) ? i : beg];   // uniform -> s_load
            m[u] = (i < end) ? 1.f : 0.f;           // scalar mask
            v[u] = hL[(long long)s * 64];
        }
#pragma unroll
        for (int u = 0; u < 16; u++) acc = fmaf(v[u], m[u], acc);
    }
    float gs = h1g[(long long)node * 64 + lane];
    float o = dvd * (acc + gs) + ldf(b1, lane, fw);
    h1b[(long long)node * 64 + lane] = __float2bfloat16(fmaxf(o, 0.f));
}

// ---------------------------------------------------------------- GEMM2 (MFMA): h1b[N,64]@W2 -> h2g[N,32] f32 (dinv-scaled)
__global__ __launch_bounds__(256, 4)
void gemm2_mfma_kernel(const short* __restrict__ h1b, const bf16* __restrict__ Bpack,
                       const float* __restrict__ dinv, float* __restrict__ h2g, int N) {
    int lane = threadIdx.x & 63, wave = threadIdx.x >> 6;
    int m = lane & 15, quad = lane >> 4;
    int r0 = blockIdx.x * 64 + wave * 16;
    if (r0 >= N) return;
    const short8* bp = (const short8*)Bpack;
    short8 B[4];
#pragma unroll
    for (int i = 0; i < 4; i++) B[i] = bp[i * 64 + lane];
    f32x4 acc0 = {0.f,0.f,0.f,0.f}, acc1 = {0.f,0.f,0.f,0.f};
    if (r0 + 16 <= N) {
        const short* xr = &h1b[(long long)(r0 + m) * 64 + quad * 8];
#pragma unroll
        for (int k = 0; k < 2; k++) {
            short8 A = *(const short8*)(xr + k * 32);
            acc0 = MFMA16(A, B[k * 2 + 0], acc0);
            acc1 = MFMA16(A, B[k * 2 + 1], acc1);
        }
        float dv[4];
#pragma unroll
        for (int r = 0; r < 4; r++) dv[r] = dinv[r0 + quad * 4 + r];
        float* o = &h2g[(long long)(r0 + quad * 4) * 32 + m];
#pragma unroll
        for (int r = 0; r < 4; r++) {
            o[(long long)r * 32] = acc0[r] * dv[r];
            o[(long long)r * 32 + 16] = acc1[r] * dv[r];
        }
    } else {
        int row = r0 + m;
#pragma unroll
        for (int k = 0; k < 2; k++) {
            short8 A = {0,0,0,0,0,0,0,0};
            if (row < N) A = *(const short8*)&h1b[(long long)row * 64 + k * 32 + quad * 8];
            acc0 = MFMA16(A, B[k * 2 + 0], acc0);
            acc1 = MFMA16(A, B[k * 2 + 1], acc1);
        }
#pragma unroll
        for (int r = 0; r < 4; r++) {
            int orow = r0 + quad * 4 + r;
            if (orow < N) {
                float dv = dinv[orow];
                h2g[(long long)orow * 32 + m] = acc0[r] * dv;
                h2g[(long long)orow * 32 + 16 + m] = acc1[r] * dv;
            }
        }
    }
}

// ---------------------------------------------------------------- gather layer 2: h2g -> h2b (bf16)
// One wave per node (uniform node -> s_load indices); the two 32-lane halves
// process alternate edges, final cross-half reduce via one shfl_xor(32).
__global__ __launch_bounds__(256, 8)
void gather2_kernel(const float* __restrict__ h2g, const float* __restrict__ dinv,
                    const int* __restrict__ rowptr, const int* __restrict__ csr_src,
                    const void* __restrict__ b2, const int* __restrict__ flags,
                    bf16* __restrict__ h2b, int N) {
    bool fw = flags[1] != 0;
    int lane = threadIdx.x & 63;
    int ch = lane & 31, half = lane >> 5;
    int wv = __builtin_amdgcn_readfirstlane(threadIdx.x >> 6);
    int node = blockIdx.x * 4 + wv;
    if (node >= N) return;
    int beg = rowptr[node], end = rowptr[node + 1];
    float dvd = dinv[node];
    const float* hL = h2g + ch;
    float acc = 0.f;
    for (int b = beg; b < end; b += 16) {
        float v[8], m[8];
#pragma unroll
        for (int u = 0; u < 8; u++) {
            int i0 = b + 2 * u, i1 = i0 + 1;
            int s0 = csr_src[(i0 < end) ? i0 : beg];  // uniform -> s_load
            int s1 = csr_src[(i1 < end) ? i1 : beg];
            float m0 = (i0 < end) ? 1.f : 0.f;
            float m1 = (i1 < end) ? 1.f : 0.f;
            int s = half ? s1 : s0;                   // per-lane select of two scalars
            m[u] = half ? m1 : m0;
            v[u] = hL[(long long)s * 32];
        }
#pragma unroll
        for (int u = 0; u < 8; u++) acc = fmaf(v[u], m[u], acc);
    }
    acc += __shfl_xor(acc, 32);
    if (half == 0) {
        float gs = h2g[(long long)node * 32 + ch];
        float o = dvd * (acc + gs) + ldf(b2, ch, fw);
        h2b[(long long)node * 32 + ch] = __float2bfloat16(o);
    }
}

// ---------------------------------------------------------------- final (MFMA): [xb|h1b|h2b]@Wl + bl -> log_softmax
__global__ __launch_bounds__(256, 2)
void final_mfma_kernel(const short* __restrict__ xb, const short* __restrict__ h1b,
                       const short* __restrict__ h2b, const bf16* __restrict__ Bpack,
                       const void* __restrict__ bl, const int* __restrict__ flags,
                       void* __restrict__ out, int N) {
    bool fw = flags[1] != 0, fx = flags[0] != 0;
    int lane = threadIdx.x & 63, wave = threadIdx.x >> 6;
    int m = lane & 15, quad = lane >> 4;
    int r0 = blockIdx.x * 64 + wave * 16;
    if (r0 >= N) return;
    const short8* bp = (const short8*)Bpack;
    short8 B[14];
#pragma unroll
    for (int i = 0; i < 14; i++) B[i] = bp[i * 64 + lane];
    f32x4 acc0 = {0.f,0.f,0.f,0.f}, acc1 = {0.f,0.f,0.f,0.f};
    bool full = (r0 + 16 <= N);
    int row = r0 + m;
    bool rowok = full || (row < N);
#pragma unroll
    for (int s = 0; s < 7; s++) {
        short8 A = {0,0,0,0,0,0,0,0};
        if (rowok) {
            const short* p;
            if (s < 4)      p = &xb [(long long)row * 128 + s * 32 + quad * 8];
            else if (s < 6) p = &h1b[(long long)row * 64 + (s - 4) * 32 + quad * 8];
            else            p = &h2b[(long long)row * 32 + quad * 8];
            A = *(const short8*)p;
        }
        acc0 = MFMA16(A, B[s * 2 + 0], acc0);
        acc1 = MFMA16(A, B[s * 2 + 1], acc1);
    }
    float bl0 = ldf(bl, m, fw), bl1 = ldf(bl, m + 16, fw);
#pragma unroll
    for (int r = 0; r < 4; r++) {
        float v0 = acc0[r] + bl0, v1 = acc1[r] + bl1;
        float mx = fmaxf(v0, v1);
#pragma unroll
        for (int o = 8; o > 0; o >>= 1) mx = fmaxf(mx, __shfl_xor(mx, o));
        float sm = __expf(v0 - mx) + __expf(v1 - mx);
#pragma unroll
        for (int o = 8; o > 0; o >>= 1) sm += __shfl_xor(sm, o);
        float lse = mx + __logf(sm);
        int orow = r0 + quad * 4 + r;
        if (orow < N) {
            if (fx) {
                ((float*)out)[(long long)orow * 32 + m]      = v0 - lse;
                ((float*)out)[(long long)orow * 32 + 16 + m] = v1 - lse;
            } else {
                ((bf16*)out)[(long long)orow * 32 + m]      = __float2bfloat16(v0 - lse);
                ((bf16*)out)[(long long)orow * 32 + 16 + m] = __float2bfloat16(v1 - lse);
            }
        }
    }
}

extern "C" void kernel_launch(void* const* d_in, const int* in_sizes, int n_in,
                              void* d_out, int out_size, void* d_ws, size_t ws_size,
                              hipStream_t stream) {
    const void* x  = d_in[0];
    const int*  ei = (const int*)d_in[1];
    const void* W1 = d_in[2];
    const void* b1 = d_in[3];
    const void* W2 = d_in[4];
    const void* b2 = d_in[5];
    const void* Wl = d_in[6];
    const void* bl = d_in[7];

    int N = in_sizes[0] / 128;
    int E = in_sizes[1] / 2;

    int shift = 9;
    while (((N + (1 << shift) - 1) >> shift) > 256 && shift < 10) shift++;
    int NB = (N + (1 << shift) - 1) >> shift;   // 196 at N=100k

    // ws layout (4B units):
    // [flags 16 | bucketCount 256 | bucketBase 272 | bcursor 256 | dinv N | rowptr N+16 |
    //  Bp1 4096 | Bp2 1024 | Bp3 3584 | csr_src E | xb N*64 |
    //  A N*64 (ebuf int2 E<=N*32; then h1g f32; later h2g f32 + h2b bf16) | h1b N*32]
    int* ip      = (int*)d_ws;
    int* flags   = ip;
    int* bucketCount = ip + 16;
    int* bucketBase  = bucketCount + 256;
    int* bcursor     = bucketBase + 272;
    float* dinv  = (float*)(bcursor + 256);
    int* rowptr  = (int*)(dinv + N);
    bf16* Bp1    = (bf16*)(rowptr + N + 16);
    bf16* Bp2    = (bf16*)((int*)Bp1 + 4096);
    bf16* Bp3    = (bf16*)((int*)Bp2 + 1024);
    int* csr_src = (int*)Bp3 + 3584;
    short* xb    = (short*)(csr_src + E);                 // N*64 ints
    int*   Ai    = (int*)xb + (size_t)N * 64;             // region A: N*64 ints
    int2*  ebuf  = (int2*)Ai;                             // E*2 ints (dead before gemm1)
    float* h1g   = (float*)Ai;
    float* h2g   = (float*)Ai;                            // alias (h1g dead after gather1)
    bf16*  h2b   = (bf16*)(Ai + (size_t)N * 48);          // upper quarter of A
    bf16*  h1b   = (bf16*)(Ai + (size_t)N * 64);          // N*32 ints

    // zero flags + bucketCount
    hipMemsetAsync(ip, 0, (16 + 256) * sizeof(int), stream);

    sniff_kernel<<<3, 256, 0, stream>>>(x, W1, ei, E, flags);

    int nchunk = (E + 4095) / 4096;
    bhist_kernel<<<nchunk, 256, 0, stream>>>(ei, E, flags, shift, NB, bucketCount);
    bscan_kernel<<<1, 256, 0, stream>>>(bucketCount, NB, bucketBase, bcursor, E);
    bpart_kernel<<<nchunk, 256, 0, stream>>>(ei, E, flags, shift, NB, bcursor, ebuf);
    bbuild_kernel<<<NB, 256, 0, stream>>>(ebuf, bucketBase, shift, N, E, rowptr, dinv, csr_src);

    repack_kernel<<<3, 256, 0, stream>>>(W1, W2, Wl, flags, Bp1, Bp2, Bp3);

    long long total8 = (long long)N * 16;   // groups of 8 elements of x
    cvt_x_kernel<<<(int)((total8 + 255) / 256), 256, 0, stream>>>(x, flags, xb, total8);

    gemm1_mfma_kernel<<<(N + 127) / 128, 256, 0, stream>>>(xb, Bp1, dinv, h1g, N);
    gather1_kernel<<<(N + 3) / 4, 256, 0, stream>>>(h1g, dinv, rowptr, csr_src, b1, flags, h1b, N);
    gemm2_mfma_kernel<<<(N + 63) / 64, 256, 0, stream>>>((const short*)h1b, Bp2, dinv, h2g, N);
    gather2_kernel<<<(N + 3) / 4, 256, 0, stream>>>(h2g, dinv, rowptr, csr_src, b2, flags, h2b, N);
    final_mfma_kernel<<<(N + 63) / 64, 256, 0, stream>>>(xb, (const short*)h1b, (const short*)h2b,
                                                         Bp3, bl, flags, d_out, N);
}

// Round 3
// 324.772 us; speedup vs baseline: 1.0690x; 1.0690x over previous
//
#include <hip/hip_runtime.h>
#include <hip/hip_bf16.h>
#include <hip/hip_fp16.h>

typedef __hip_bfloat16 bf16;
typedef __attribute__((ext_vector_type(8))) short short8;   // 8 bf16 (4 VGPRs)
typedef __attribute__((ext_vector_type(4))) float f32x4;    // MFMA accumulator

#define MFMA16(a, b, c) __builtin_amdgcn_mfma_f32_16x16x32_bf16((a), (b), (c), 0, 0, 0)

// dual-mode float load: f32 ? float buffer : bf16 buffer (same element index)
static __device__ __forceinline__ float ldf(const void* p, long long i, bool f32) {
    return f32 ? ((const float*)p)[i] : __bfloat162float(((const bf16*)p)[i]);
}

static __device__ __forceinline__ short f2bs(float v) {
    union { bf16 h; short s; } u; u.h = __float2bfloat16(v); return u.s;
}

static __device__ __forceinline__ unsigned int pack_bf16x2(float a, float b) {
    return (unsigned int)(unsigned short)f2bs(a) | ((unsigned int)(unsigned short)f2bs(b) << 16);
}

// ---------------------------------------------------------------- encoding sniffer
// flags[0]: x is fp32?  flags[1]: weights are fp32?  flags[2]: edge_index is int64?
// MEASURED (R1 NaN-fail + R8 gating probe): this harness delivers x=fp32, W=fp32, out=fp32.
__global__ __launch_bounds__(256, 4)
void sniff_kernel(const void* __restrict__ x, const void* __restrict__ w,
                  const int* __restrict__ ei, int E, int* __restrict__ flags) {
    __shared__ int cnt;
    if (threadIdx.x == 0) cnt = 0;
    __syncthreads();
    if (blockIdx.x < 2) {
        const unsigned short* u = (const unsigned short*)(blockIdx.x == 0 ? x : w);
        int bad = 0;
        for (int i = threadIdx.x; i < 4096; i += 256) {
            unsigned e = (u[i] >> 7) & 0xFF;
            if (e >= 0xA0) bad++;
        }
        atomicAdd(&cnt, bad);
        __syncthreads();
        if (threadIdx.x == 0) flags[blockIdx.x] = (cnt > 16) ? 1 : 0;
    } else {
        int nz = 0;
        for (int i = threadIdx.x; i < 1024; i += 256)
            if (ei[2 * i + 1] != 0) nz++;
        atomicAdd(&cnt, nz);
        __syncthreads();
        if (threadIdx.x == 0) flags[2] = (cnt == 0) ? 1 : 0;
    }
}

static __device__ __forceinline__ int ld_src(const int* ei, int E, int e, bool i64) {
    return i64 ? ei[2 * e] : ei[e];
}
static __device__ __forceinline__ int ld_dst(const int* ei, int E, int e, bool i64) {
    return i64 ? ei[2 * (E + e)] : ei[E + e];
}

// ---------------------------------------------------------------- bucket CSR build
// shift=9: bucket b owns dst in [b*512, (b+1)*512). NB = ceil(N/512) <= 256.

// Pass A: global bucket histogram (LDS hist per block, 1 global add per bucket)
__global__ __launch_bounds__(256, 4)
void bhist_kernel(const int* __restrict__ ei, int E, const int* __restrict__ flags,
                  int shift, int NB, int* __restrict__ bucketCount) {
    __shared__ int h[256];
    for (int i = threadIdx.x; i < 256; i += 256) h[i] = 0;
    __syncthreads();
    bool i64 = flags[2] != 0;
    int base = blockIdx.x * 4096;
    for (int i = 0; i < 16; i++) {
        int e = base + i * 256 + threadIdx.x;
        if (e < E) atomicAdd(&h[ld_dst(ei, E, e, i64) >> shift], 1);
    }
    __syncthreads();
    for (int i = threadIdx.x; i < NB; i += 256)
        if (h[i]) atomicAdd(&bucketCount[i], h[i]);
}

// Pass B scan: bucketBase = exclusive scan; bcursor seeded with bases
__global__ __launch_bounds__(256, 4)
void bscan_kernel(const int* __restrict__ bucketCount, int NB,
                  int* __restrict__ bucketBase, int* __restrict__ bcursor, int E) {
    __shared__ int bs[256];
    int v = ((int)threadIdx.x < NB) ? bucketCount[threadIdx.x] : 0;
    bs[threadIdx.x] = v;
    __syncthreads();
    for (int off = 1; off < 256; off <<= 1) {
        int t = ((int)threadIdx.x >= off) ? bs[threadIdx.x - off] : 0;
        __syncthreads();
        bs[threadIdx.x] += t;
        __syncthreads();
    }
    int excl = bs[threadIdx.x] - v;
    if ((int)threadIdx.x < NB) { bucketBase[threadIdx.x] = excl; bcursor[threadIdx.x] = excl; }
    if (threadIdx.x == 0) bucketBase[NB] = E;
}

// Pass C: partition edges into bucket-contiguous ebuf (int2: x=src, y=dst)
__global__ __launch_bounds__(256, 4)
void bpart_kernel(const int* __restrict__ ei, int E, const int* __restrict__ flags,
                  int shift, int NB, int* __restrict__ bcursor, int2* __restrict__ ebuf) {
    __shared__ int h[256];
    __shared__ int gofs[256];
    for (int i = threadIdx.x; i < 256; i += 256) h[i] = 0;
    __syncthreads();
    bool i64 = flags[2] != 0;
    int base = blockIdx.x * 4096;
    // sweep 1: local histogram
    for (int i = 0; i < 16; i++) {
        int e = base + i * 256 + threadIdx.x;
        if (e < E) atomicAdd(&h[ld_dst(ei, E, e, i64) >> shift], 1);
    }
    __syncthreads();
    // claim contiguous global ranges (1 atomic per bucket per block)
    if ((int)threadIdx.x < NB) {
        int c = h[threadIdx.x];
        gofs[threadIdx.x] = c ? atomicAdd(&bcursor[threadIdx.x], c) : 0;
    }
    __syncthreads();
    for (int i = threadIdx.x; i < 256; i += 256) h[i] = 0;
    __syncthreads();
    // sweep 2: write edges into claimed dense runs
    for (int i = 0; i < 16; i++) {
        int e = base + i * 256 + threadIdx.x;
        if (e < E) {
            int s = ld_src(ei, E, e, i64), d = ld_dst(ei, E, e, i64);
            int b = d >> shift;
            int p = atomicAdd(&h[b], 1);
            ebuf[gofs[b] + p] = make_int2(s, d);
        }
    }
}

// Pass D: one block per bucket — local count, scan, rowptr+dinv write, csr fill.
// All csr writes land in one block's ~32KB window (single XCD L2; no line ping-pong).
__global__ __launch_bounds__(256, 2)
void bbuild_kernel(const int2* __restrict__ ebuf, const int* __restrict__ bucketBase,
                   int shift, int N, int E, int* __restrict__ rowptr,
                   float* __restrict__ dinv, int* __restrict__ csr_src) {
    __shared__ int cnt[1024];
    __shared__ int exc[1024];
    __shared__ int bs[256];
    int b = blockIdx.x;
    int nodeBase = b << shift;
    int width = 1 << shift;
    int nn = N - nodeBase; if (nn > width) nn = width;
    int beg = bucketBase[b], end = bucketBase[b + 1];
    for (int i = threadIdx.x; i < width; i += 256) cnt[i] = 0;
    __syncthreads();
    for (int e = beg + threadIdx.x; e < end; e += 256)
        atomicAdd(&cnt[ebuf[e].y - nodeBase], 1);
    __syncthreads();
    // exclusive scan of cnt[0..width)
    int per = width / 256;          // 2 at shift=9
    int s = 0;
    int base4 = threadIdx.x * per;
    for (int i = 0; i < per; i++) s += cnt[base4 + i];
    bs[threadIdx.x] = s;
    __syncthreads();
    for (int off = 1; off < 256; off <<= 1) {
        int t = ((int)threadIdx.x >= off) ? bs[threadIdx.x - off] : 0;
        __syncthreads();
        bs[threadIdx.x] += t;
        __syncthreads();
    }
    int run = bs[threadIdx.x] - s;
    for (int i = 0; i < per; i++) { exc[base4 + i] = run; run += cnt[base4 + i]; }
    __syncthreads();
    // rowptr + dinv (coalesced)
    for (int i = threadIdx.x; i < nn; i += 256) {
        int node = nodeBase + i;
        rowptr[node] = beg + exc[i];
        dinv[node] = rsqrtf((float)cnt[i] + 1.0f);
    }
    __syncthreads();
    for (int i = threadIdx.x; i < width; i += 256) cnt[i] = 0;
    __syncthreads();
    // csr fill within local window
    for (int e = beg + threadIdx.x; e < end; e += 256) {
        int2 v = ebuf[e];
        int l = v.y - nodeBase;
        int p = atomicAdd(&cnt[l], 1);
        csr_src[beg + exc[l] + p] = v.x;
    }
    if (b == 0 && threadIdx.x == 0) rowptr[N] = E;
}

// ---------------------------------------------------------------- weight -> MFMA B-fragment packs
// frag f = kstep*ntiles + ntile; slot s = f*64 + lane; element j (0..7):
//   W[kstep*32 + (lane>>4)*8 + j][ntile*16 + (lane&15)]  (fw-aware fp32/bf16 read)
__global__ __launch_bounds__(256, 4)
void repack_kernel(const void* __restrict__ W1, const void* __restrict__ W2,
                   const void* __restrict__ Wl, const int* __restrict__ flags,
                   bf16* __restrict__ Bp1, bf16* __restrict__ Bp2, bf16* __restrict__ Bp3) {
    bool fw = flags[1] != 0;
    const void* W; bf16* Bp; int ntiles, nc, nfrag;
    if (blockIdx.x == 0)      { W = W1; Bp = Bp1; ntiles = 4; nc = 64; nfrag = 16; }
    else if (blockIdx.x == 1) { W = W2; Bp = Bp2; ntiles = 2; nc = 32; nfrag = 4;  }
    else                      { W = Wl; Bp = Bp3; ntiles = 2; nc = 32; nfrag = 14; }
    for (int s = threadIdx.x; s < nfrag * 64; s += 256) {
        int f = s >> 6, lane = s & 63;
        int kstep = f / ntiles, ntile = f % ntiles;
        int n = ntile * 16 + (lane & 15);
        int kbase = kstep * 32 + (lane >> 4) * 8;
#pragma unroll
        for (int j = 0; j < 8; j++)
            Bp[s * 8 + j] = __float2bfloat16(ldf(W, (long long)(kbase + j) * nc + n, fw));
    }
}

// ---------------------------------------------------------------- x -> xb (bf16), both source dtypes
__global__ __launch_bounds__(256, 4)
void cvt_x_kernel(const void* __restrict__ x, const int* __restrict__ flags,
                  short* __restrict__ xb, long long total8) {
    long long i = (long long)blockIdx.x * 256 + threadIdx.x;
    if (i >= total8) return;
    bool fx = flags[0] != 0;
    short8 o;
    if (fx) {
        const float4* xf = (const float4*)x;
        float4 a = xf[i * 2], b = xf[i * 2 + 1];
        o[0] = f2bs(a.x); o[1] = f2bs(a.y); o[2] = f2bs(a.z); o[3] = f2bs(a.w);
        o[4] = f2bs(b.x); o[5] = f2bs(b.y); o[6] = f2bs(b.z); o[7] = f2bs(b.w);
    } else {
        o = ((const short8*)x)[i];
    }
    ((short8*)xb)[i] = o;
}

// ---------------------------------------------------------------- GEMM1 (MFMA): xb[N,128]@W1 -> h1g[N,64] f16 rows
// Epilogue scales row r by dinv[r] and stores f16 (rel err 2^-11, negligible vs
// the bf16 rounding already applied downstream).  128B rows halve the gather's
// L2-miss volume (the measured 3.7 TB/s wall is miss-volume-bound).
__global__ __launch_bounds__(256, 3)
void gemm1_mfma_kernel(const short* __restrict__ xb, const bf16* __restrict__ Bpack,
                       const float* __restrict__ dinv, __half* __restrict__ h1g, int N) {
    int lane = threadIdx.x & 63, wave = threadIdx.x >> 6;
    int m = lane & 15, quad = lane >> 4;
    int base = blockIdx.x * 128 + wave * 32;
    if (base >= N) return;
    const short8* bp = (const short8*)Bpack;
    short8 B[16];
#pragma unroll
    for (int i = 0; i < 16; i++) B[i] = bp[i * 64 + lane];
    if (base + 32 <= N) {
#pragma unroll
        for (int t = 0; t < 2; t++) {
            int r0 = base + t * 16;
            const short* xr = &xb[(long long)(r0 + m) * 128 + quad * 8];
            short8 A[4];
#pragma unroll
            for (int k = 0; k < 4; k++) A[k] = *(const short8*)(xr + k * 32);
            f32x4 acc[4];
#pragma unroll
            for (int nt = 0; nt < 4; nt++) acc[nt] = (f32x4){0.f, 0.f, 0.f, 0.f};
#pragma unroll
            for (int k = 0; k < 4; k++) {
#pragma unroll
                for (int nt = 0; nt < 4; nt++) acc[nt] = MFMA16(A[k], B[k * 4 + nt], acc[nt]);
            }
            // C/D: col = lane&15, row = quad*4 + r  [m89/m91]
            float dv[4];
#pragma unroll
            for (int r = 0; r < 4; r++) dv[r] = dinv[r0 + quad * 4 + r];
            __half* o = &h1g[(long long)(r0 + quad * 4) * 64 + m];
#pragma unroll
            for (int nt = 0; nt < 4; nt++) {
#pragma unroll
                for (int r = 0; r < 4; r++) o[(long long)r * 64 + nt * 16] = __float2half(acc[nt][r] * dv[r]);
            }
        }
    } else {
#pragma unroll
        for (int t = 0; t < 2; t++) {
            int r0 = base + t * 16;
            int row = r0 + m;
            short8 A[4];
#pragma unroll
            for (int k = 0; k < 4; k++) A[k] = (short8){0,0,0,0,0,0,0,0};
            if (row < N) {
                const short* xr = &xb[(long long)row * 128 + quad * 8];
#pragma unroll
                for (int k = 0; k < 4; k++) A[k] = *(const short8*)(xr + k * 32);
            }
            f32x4 acc[4];
#pragma unroll
            for (int nt = 0; nt < 4; nt++) acc[nt] = (f32x4){0.f, 0.f, 0.f, 0.f};
#pragma unroll
            for (int k = 0; k < 4; k++) {
#pragma unroll
                for (int nt = 0; nt < 4; nt++) acc[nt] = MFMA16(A[k], B[k * 4 + nt], acc[nt]);
            }
#pragma unroll
            for (int r = 0; r < 4; r++) {
                int orow = r0 + quad * 4 + r;
                if (orow < N) {
                    float dv = dinv[orow];
                    __half* o = &h1g[(long long)orow * 64 + m];
#pragma unroll
                    for (int nt = 0; nt < 4; nt++) o[nt * 16] = __float2half(acc[nt][r] * dv);
                }
            }
        }
    }
}

// ---------------------------------------------------------------- gather layer 1: one wave per node -> h1b (bf16 packed)
// f16x2-packed 128B rows: half-wave (32 lanes x 4B) per edge, 2 edges per wave
// step, 16 edges per unrolled iter (16 row-loads in flight).  Indices via
// uniform s_load (round-2 win); per-edge weights factored into GEMM epilogue.
// Cross-half reduce via one shfl_xor(32); half 0 stores 128B packed bf16x2.
__global__ __launch_bounds__(256, 8)
void gather1_kernel(const unsigned int* __restrict__ h1g, const float* __restrict__ dinv,
                    const int* __restrict__ rowptr, const int* __restrict__ csr_src,
                    const void* __restrict__ b1, const int* __restrict__ flags,
                    unsigned int* __restrict__ h1b, int N) {
    bool fw = flags[1] != 0;
    int lane = threadIdx.x & 63;
    int c = lane & 31, hf = lane >> 5;
    int wv = __builtin_amdgcn_readfirstlane(threadIdx.x >> 6);
    int node = blockIdx.x * 4 + wv;
    if (node >= N) return;
    int beg = rowptr[node], end = rowptr[node + 1];
    float dvd = dinv[node];
    const unsigned int* hL = h1g + c;
    float a0 = 0.f, a1 = 0.f;
    for (int b = beg; b < end; b += 16) {
        unsigned int v[8]; float m[8];
#pragma unroll
        for (int u = 0; u < 8; u++) {
            int i0 = b + 2 * u, i1 = i0 + 1;
            int s0 = csr_src[(i0 < end) ? i0 : beg];   // uniform -> s_load
            int s1 = csr_src[(i1 < end) ? i1 : beg];
            float m0 = (i0 < end) ? 1.f : 0.f;
            float m1 = (i1 < end) ? 1.f : 0.f;
            int s = hf ? s1 : s0;
            m[u] = hf ? m1 : m0;
            v[u] = hL[(long long)s * 32];
        }
#pragma unroll
        for (int u = 0; u < 8; u++) {
            float2 f = __half22float2(*(const __half2*)&v[u]);
            a0 = fmaf(f.x, m[u], a0);
            a1 = fmaf(f.y, m[u], a1);
        }
    }
    a0 += __shfl_xor(a0, 32);
    a1 += __shfl_xor(a1, 32);
    if (hf == 0) {
        unsigned int gsv = h1g[(long long)node * 32 + c];
        float2 gs = __half22float2(*(const __half2*)&gsv);
        float o0 = dvd * (a0 + gs.x) + ldf(b1, 2 * c, fw);
        float o1 = dvd * (a1 + gs.y) + ldf(b1, 2 * c + 1, fw);
        h1b[(long long)node * 32 + c] = pack_bf16x2(fmaxf(o0, 0.f), fmaxf(o1, 0.f));
    }
}

// ---------------------------------------------------------------- GEMM2 (MFMA): h1b[N,64]@W2 -> h2g[N,32] f16 rows (dinv-scaled)
__global__ __launch_bounds__(256, 4)
void gemm2_mfma_kernel(const short* __restrict__ h1b, const bf16* __restrict__ Bpack,
                       const float* __restrict__ dinv, __half* __restrict__ h2g, int N) {
    int lane = threadIdx.x & 63, wave = threadIdx.x >> 6;
    int m = lane & 15, quad = lane >> 4;
    int r0 = blockIdx.x * 64 + wave * 16;
    if (r0 >= N) return;
    const short8* bp = (const short8*)Bpack;
    short8 B[4];
#pragma unroll
    for (int i = 0; i < 4; i++) B[i] = bp[i * 64 + lane];
    f32x4 acc0 = {0.f,0.f,0.f,0.f}, acc1 = {0.f,0.f,0.f,0.f};
    if (r0 + 16 <= N) {
        const short* xr = &h1b[(long long)(r0 + m) * 64 + quad * 8];
#pragma unroll
        for (int k = 0; k < 2; k++) {
            short8 A = *(const short8*)(xr + k * 32);
            acc0 = MFMA16(A, B[k * 2 + 0], acc0);
            acc1 = MFMA16(A, B[k * 2 + 1], acc1);
        }
        float dv[4];
#pragma unroll
        for (int r = 0; r < 4; r++) dv[r] = dinv[r0 + quad * 4 + r];
        __half* o = &h2g[(long long)(r0 + quad * 4) * 32 + m];
#pragma unroll
        for (int r = 0; r < 4; r++) {
            o[(long long)r * 32]      = __float2half(acc0[r] * dv[r]);
            o[(long long)r * 32 + 16] = __float2half(acc1[r] * dv[r]);
        }
    } else {
        int row = r0 + m;
#pragma unroll
        for (int k = 0; k < 2; k++) {
            short8 A = {0,0,0,0,0,0,0,0};
            if (row < N) A = *(const short8*)&h1b[(long long)row * 64 + k * 32 + quad * 8];
            acc0 = MFMA16(A, B[k * 2 + 0], acc0);
            acc1 = MFMA16(A, B[k * 2 + 1], acc1);
        }
#pragma unroll
        for (int r = 0; r < 4; r++) {
            int orow = r0 + quad * 4 + r;
            if (orow < N) {
                float dv = dinv[orow];
                h2g[(long long)orow * 32 + m]      = __float2half(acc0[r] * dv);
                h2g[(long long)orow * 32 + 16 + m] = __float2half(acc1[r] * dv);
            }
        }
    }
}

// ---------------------------------------------------------------- gather layer 2: h2g (f16x2, 64B rows) -> h2b (bf16 packed)
// 16-lane group per edge (16 x 4B = 64B row), 4 edges per wave step, 16 per
// unrolled iter.  Two-level cross-group reduce; group 0 stores 64B packed.
__global__ __launch_bounds__(256, 8)
void gather2_kernel(const unsigned int* __restrict__ h2g, const float* __restrict__ dinv,
                    const int* __restrict__ rowptr, const int* __restrict__ csr_src,
                    const void* __restrict__ b2, const int* __restrict__ flags,
                    unsigned int* __restrict__ h2b, int N) {
    bool fw = flags[1] != 0;
    int lane = threadIdx.x & 63;
    int c = lane & 15, sub = lane >> 4;
    int wv = __builtin_amdgcn_readfirstlane(threadIdx.x >> 6);
    int node = blockIdx.x * 4 + wv;
    if (node >= N) return;
    int beg = rowptr[node], end = rowptr[node + 1];
    float dvd = dinv[node];
    const unsigned int* hL = h2g + c;
    float a0 = 0.f, a1 = 0.f;
    for (int b = beg; b < end; b += 16) {
        unsigned int v[4]; float m[4];
#pragma unroll
        for (int u = 0; u < 4; u++) {
            int i0 = b + 4 * u;
            int s0 = csr_src[(i0     < end) ? i0     : beg];   // uniform -> s_load
            int s1 = csr_src[(i0 + 1 < end) ? i0 + 1 : beg];
            int s2 = csr_src[(i0 + 2 < end) ? i0 + 2 : beg];
            int s3 = csr_src[(i0 + 3 < end) ? i0 + 3 : beg];
            int sa = (sub & 1) ? s1 : s0;
            int sb = (sub & 1) ? s3 : s2;
            int s  = (sub & 2) ? sb : sa;
            float ma = (sub & 1) ? ((i0 + 1 < end) ? 1.f : 0.f) : ((i0 < end) ? 1.f : 0.f);
            float mb = (sub & 1) ? ((i0 + 3 < end) ? 1.f : 0.f) : ((i0 + 2 < end) ? 1.f : 0.f);
            m[u] = (sub & 2) ? mb : ma;
            v[u] = hL[(long long)s * 16];
        }
#pragma unroll
        for (int u = 0; u < 4; u++) {
            float2 f = __half22float2(*(const __half2*)&v[u]);
            a0 = fmaf(f.x, m[u], a0);
            a1 = fmaf(f.y, m[u], a1);
        }
    }
    a0 += __shfl_xor(a0, 16); a1 += __shfl_xor(a1, 16);
    a0 += __shfl_xor(a0, 32); a1 += __shfl_xor(a1, 32);
    if (sub == 0) {
        unsigned int gsv = h2g[(long long)node * 16 + c];
        float2 gs = __half22float2(*(const __half2*)&gsv);
        float o0 = dvd * (a0 + gs.x) + ldf(b2, 2 * c, fw);
        float o1 = dvd * (a1 + gs.y) + ldf(b2, 2 * c + 1, fw);
        h2b[(long long)node * 16 + c] = pack_bf16x2(o0, o1);
    }
}

// ---------------------------------------------------------------- final (MFMA): [xb|h1b|h2b]@Wl + bl -> log_softmax
__global__ __launch_bounds__(256, 2)
void final_mfma_kernel(const short* __restrict__ xb, const short* __restrict__ h1b,
                       const short* __restrict__ h2b, const bf16* __restrict__ Bpack,
                       const void* __restrict__ bl, const int* __restrict__ flags,
                       void* __restrict__ out, int N) {
    bool fw = flags[1] != 0, fx = flags[0] != 0;
    int lane = threadIdx.x & 63, wave = threadIdx.x >> 6;
    int m = lane & 15, quad = lane >> 4;
    int r0 = blockIdx.x * 64 + wave * 16;
    if (r0 >= N) return;
    const short8* bp = (const short8*)Bpack;
    short8 B[14];
#pragma unroll
    for (int i = 0; i < 14; i++) B[i] = bp[i * 64 + lane];
    f32x4 acc0 = {0.f,0.f,0.f,0.f}, acc1 = {0.f,0.f,0.f,0.f};
    bool full = (r0 + 16 <= N);
    int row = r0 + m;
    bool rowok = full || (row < N);
#pragma unroll
    for (int s = 0; s < 7; s++) {
        short8 A = {0,0,0,0,0,0,0,0};
        if (rowok) {
            const short* p;
            if (s < 4)      p = &xb [(long long)row * 128 + s * 32 + quad * 8];
            else if (s < 6) p = &h1b[(long long)row * 64 + (s - 4) * 32 + quad * 8];
            else            p = &h2b[(long long)row * 32 + quad * 8];
            A = *(const short8*)p;
        }
        acc0 = MFMA16(A, B[s * 2 + 0], acc0);
        acc1 = MFMA16(A, B[s * 2 + 1], acc1);
    }
    float bl0 = ldf(bl, m, fw), bl1 = ldf(bl, m + 16, fw);
#pragma unroll
    for (int r = 0; r < 4; r++) {
        float v0 = acc0[r] + bl0, v1 = acc1[r] + bl1;
        float mx = fmaxf(v0, v1);
#pragma unroll
        for (int o = 8; o > 0; o >>= 1) mx = fmaxf(mx, __shfl_xor(mx, o));
        float sm = __expf(v0 - mx) + __expf(v1 - mx);
#pragma unroll
        for (int o = 8; o > 0; o >>= 1) sm += __shfl_xor(sm, o);
        float lse = mx + __logf(sm);
        int orow = r0 + quad * 4 + r;
        if (orow < N) {
            if (fx) {
                ((float*)out)[(long long)orow * 32 + m]      = v0 - lse;
                ((float*)out)[(long long)orow * 32 + 16 + m] = v1 - lse;
            } else {
                ((bf16*)out)[(long long)orow * 32 + m]      = __float2bfloat16(v0 - lse);
                ((bf16*)out)[(long long)orow * 32 + 16 + m] = __float2bfloat16(v1 - lse);
            }
        }
    }
}

extern "C" void kernel_launch(void* const* d_in, const int* in_sizes, int n_in,
                              void* d_out, int out_size, void* d_ws, size_t ws_size,
                              hipStream_t stream) {
    const void* x  = d_in[0];
    const int*  ei = (const int*)d_in[1];
    const void* W1 = d_in[2];
    const void* b1 = d_in[3];
    const void* W2 = d_in[4];
    const void* b2 = d_in[5];
    const void* Wl = d_in[6];
    const void* bl = d_in[7];

    int N = in_sizes[0] / 128;
    int E = in_sizes[1] / 2;

    int shift = 9;
    while (((N + (1 << shift) - 1) >> shift) > 256 && shift < 10) shift++;
    int NB = (N + (1 << shift) - 1) >> shift;   // 196 at N=100k

    // ws layout (4B units):
    // [flags 16 | bucketCount 256 | bucketBase 272 | bcursor 256 | dinv N | rowptr N+16 |
    //  Bp1 4096 | Bp2 1024 | Bp3 3584 | csr_src E | xb N*64 |
    //  A N*64 (ebuf int2 E<=N*32; then h1g f16 N*32; later h2g f16 N*16 + h2b N*16) | h1b N*32]
    int* ip      = (int*)d_ws;
    int* flags   = ip;
    int* bucketCount = ip + 16;
    int* bucketBase  = bucketCount + 256;
    int* bcursor     = bucketBase + 272;
    float* dinv  = (float*)(bcursor + 256);
    int* rowptr  = (int*)(dinv + N);
    bf16* Bp1    = (bf16*)(rowptr + N + 16);
    bf16* Bp2    = (bf16*)((int*)Bp1 + 4096);
    bf16* Bp3    = (bf16*)((int*)Bp2 + 1024);
    int* csr_src = (int*)Bp3 + 3584;
    short* xb    = (short*)(csr_src + E);                 // N*64 ints
    int*   Ai    = (int*)xb + (size_t)N * 64;             // region A: N*64 ints
    int2*  ebuf  = (int2*)Ai;                             // E*2 ints (dead before gemm1)
    __half* h1g  = (__half*)Ai;                           // N*64 halves = N*32 ints
    __half* h2g  = (__half*)Ai;                           // alias (h1g dead after gather1), N*16 ints
    unsigned int* h2b = (unsigned int*)(Ai + (size_t)N * 48);  // N*16 uints
    unsigned int* h1b = (unsigned int*)(Ai + (size_t)N * 64);  // N*32 uints

    // zero flags + bucketCount
    hipMemsetAsync(ip, 0, (16 + 256) * sizeof(int), stream);

    sniff_kernel<<<3, 256, 0, stream>>>(x, W1, ei, E, flags);

    int nchunk = (E + 4095) / 4096;
    bhist_kernel<<<nchunk, 256, 0, stream>>>(ei, E, flags, shift, NB, bucketCount);
    bscan_kernel<<<1, 256, 0, stream>>>(bucketCount, NB, bucketBase, bcursor, E);
    bpart_kernel<<<nchunk, 256, 0, stream>>>(ei, E, flags, shift, NB, bcursor, ebuf);
    bbuild_kernel<<<NB, 256, 0, stream>>>(ebuf, bucketBase, shift, N, E, rowptr, dinv, csr_src);

    repack_kernel<<<3, 256, 0, stream>>>(W1, W2, Wl, flags, Bp1, Bp2, Bp3);

    long long total8 = (long long)N * 16;   // groups of 8 elements of x
    cvt_x_kernel<<<(int)((total8 + 255) / 256), 256, 0, stream>>>(x, flags, xb, total8);

    gemm1_mfma_kernel<<<(N + 127) / 128, 256, 0, stream>>>(xb, Bp1, dinv, h1g, N);
    gather1_kernel<<<(N + 3) / 4, 256, 0, stream>>>((const unsigned int*)h1g, dinv, rowptr, csr_src,
                                                    b1, flags, h1b, N);
    gemm2_mfma_kernel<<<(N + 63) / 64, 256, 0, stream>>>((const short*)h1b, Bp2, dinv, h2g, N);
    gather2_kernel<<<(N + 3) / 4, 256, 0, stream>>>((const unsigned int*)h2g, dinv, rowptr, csr_src,
                                                    b2, flags, h2b, N);
    final_mfma_kernel<<<(N + 63) / 64, 256, 0, stream>>>(xb, (const short*)h1b, (const short*)h2b,
                                                         Bp3, bl, flags, d_out, N);
}